// Round 4
// baseline (518.234 us; speedup 1.0000x reference)
//
#include <hip/hip_runtime.h>
#include <cstdint>
#include <cstddef>

#define B_  64
#define D_  1024
#define S_  512
#define K_  100
#define KP_ 128
#define H_  2048
#define BS_ (B_*S_)   // 32768

// ---- workspace layout (float offsets) ----
static constexpr size_t OFF_TVN  = 0;                          // [1024][128] padded normalized topics
static constexpr size_t OFF_TPNT = 131072;                     // [100][32768] topic_prob_n transposed
static constexpr size_t OFF_HSUM = OFF_TPNT + (size_t)K_*BS_;  // [64][2048]
static constexpr size_t OFF_INTS = OFF_HSUM + (size_t)B_*H_;   // int region: cnt, bact[64], alist[32768]

// ---------------------------------------------------------------------------
// prep: blocks 0..127 normalize topic columns -> tvn[1024][128] (pad cols 0);
//       blocks 128..639 zero hsum; block 640: out scalar init + ints zero.
__global__ __launch_bounds__(256) void prep_kernel(
    const float* __restrict__ tv, const float* __restrict__ bc,
    float* __restrict__ tvn, float* __restrict__ hsum,
    int* __restrict__ ints, float* __restrict__ out)
{
    __shared__ float red[256];
    const int tid = threadIdx.x;
    const int blk = blockIdx.x;
    if (blk < KP_) {
        const int k = blk;
        if (k >= K_) {
            for (int d = tid; d < D_; d += 256) tvn[d*KP_ + k] = 0.f;
            return;
        }
        float ss = 0.f;
        for (int d = tid; d < D_; d += 256) { float v = tv[d*K_ + k]; ss = fmaf(v, v, ss); }
        red[tid] = ss;
        __syncthreads();
        for (int s = 128; s > 0; s >>= 1) {
            if (tid < s) red[tid] += red[tid + s];
            __syncthreads();
        }
        const float inv = 1.0f / fmaxf(sqrtf(red[0]), 1e-12f);
        for (int d = tid; d < D_; d += 256) tvn[d*KP_ + k] = tv[d*K_ + k] * inv;
        return;
    }
    if (blk < KP_ + 512) {
        hsum[(blk - KP_)*256 + tid] = 0.f;       // 512*256 == B_*H_
        return;
    }
    // scalar init block
    if (tid < 128)      out[tid] = bc[tid & 1];  // pred = b_cls (atomics add partials)
    else if (tid < 131) out[tid] = 0.f;          // out[128]=0, sim=0 (+atomics), far placeholder
    if (tid < 65) ints[tid] = 0;                 // cnt + bact[64]
}

// ---------------------------------------------------------------------------
// gemm1: topic_prob = f^T . tvn (fp32 VALU GEMM) with NO LDS staging and NO
// main-loop barriers: both operands read straight from global (L1/L2-served,
// lane-duplicated reads coalesce). Compiler software-pipelines the unrolled
// d-loop with counted vmcnt — latency hidden by ILP + 8 waves/CU.
// Grid 512 = 64 b x 8 s-tiles(64). Block 256 threads (4 waves).
// Per-thread tile 4s x 8k (32 acc). Row-norms accumulate off the f loads.
__global__ __launch_bounds__(256, 2) void gemm1_kernel(
    const float* __restrict__ f, const float* __restrict__ tvn,
    float* __restrict__ out_nn, float* __restrict__ tpnT,
    int* __restrict__ cnt, int* __restrict__ bact, int* __restrict__ alist)
{
    __shared__ float red[16*64];          // rowsum reduction scratch (4 KB)
    __shared__ float ninv[64];
    __shared__ float rinv[64];

    const int tid = threadIdx.x;
    const int b   = blockIdx.x >> 3;
    const int s0  = (blockIdx.x & 7) << 6;
    const int sg  = tid & 15;             // s-quad: s = s0 + sg*4 + r
    const int kg  = tid >> 4;             // k-octet: k = kg*8 + j

    const float* fp = f + (size_t)b * D_ * S_ + s0 + sg*4;
    const float* tp = tvn + kg*8;

    float acc[4][8];
#pragma unroll
    for (int r = 0; r < 4; ++r)
#pragma unroll
        for (int j = 0; j < 8; ++j) acc[r][j] = 0.f;
    float nsq[4] = {0.f, 0.f, 0.f, 0.f};

#pragma unroll 8
    for (int d = 0; d < D_; ++d) {
        const float4 a  = *(const float4*)(fp + (size_t)d * S_);
        const float4 w0 = *(const float4*)(tp + d*KP_);
        const float4 w1 = *(const float4*)(tp + d*KP_ + 4);
        nsq[0] = fmaf(a.x, a.x, nsq[0]);
        nsq[1] = fmaf(a.y, a.y, nsq[1]);
        nsq[2] = fmaf(a.z, a.z, nsq[2]);
        nsq[3] = fmaf(a.w, a.w, nsq[3]);
        const float w[8] = {w0.x,w0.y,w0.z,w0.w,w1.x,w1.y,w1.z,w1.w};
#pragma unroll
        for (int j = 0; j < 8; ++j) {
            acc[0][j] = fmaf(a.x, w[j], acc[0][j]);
            acc[1][j] = fmaf(a.y, w[j], acc[1][j]);
            acc[2][j] = fmaf(a.z, w[j], acc[2][j]);
            acc[3][j] = fmaf(a.w, w[j], acc[3][j]);
        }
    }

    // ---- epilogue ----
    // row norms: every thread summed the full d-range for its s-quad, so the
    // kg==0 threads (tid<16) hold complete, correct norms already.
    if (tid < 16) {
#pragma unroll
        for (int r = 0; r < 4; ++r)
            ninv[tid*4 + r] = 1.0f / fmaxf(sqrtf(nsq[r]), 1e-12f);
    }
    __syncthreads();

    const int bs0 = b * S_ + s0;
    const float inv0 = ninv[sg*4], inv1 = ninv[sg*4+1], inv2 = ninv[sg*4+2], inv3 = ninv[sg*4+3];
    float rowp[4] = {0.f, 0.f, 0.f, 0.f};

#pragma unroll
    for (int j = 0; j < 8; ++j) {
        const int k = kg*8 + j;
        const float t0 = acc[0][j]*inv0, t1 = acc[1][j]*inv1,
                    t2 = acc[2][j]*inv2, t3 = acc[3][j]*inv3;
        acc[0][j] = (t0 > 0.3f) ? acc[0][j] : 0.f;   // topic_prob * mask
        acc[1][j] = (t1 > 0.3f) ? acc[1][j] : 0.f;
        acc[2][j] = (t2 > 0.3f) ? acc[2][j] : 0.f;
        acc[3][j] = (t3 > 0.3f) ? acc[3][j] : 0.f;
        rowp[0] += acc[0][j]; rowp[1] += acc[1][j];
        rowp[2] += acc[2][j]; rowp[3] += acc[3][j];
        if (k < K_) {                     // topic_prob_n transposed (coalesced float4)
            float4 v; v.x = t0; v.y = t1; v.z = t2; v.w = t3;
            *(float4*)&tpnT[(size_t)k * BS_ + bs0 + sg*4] = v;
        }
    }

    // row sums: reduce across 16 k-groups
#pragma unroll
    for (int r = 0; r < 4; ++r) red[kg*64 + sg*4 + r] = rowp[r];
    __syncthreads();
    if (tid < 64) {
        float t = 0.f;
#pragma unroll
        for (int g = 0; g < 16; ++g) t += red[g*64 + tid];
        rinv[tid] = 1.0f / (t + 0.001f);
        if (t > 0.f) {                    // any unmasked concept in this row
            const int pos = atomicAdd(cnt, 1);
            alist[pos] = bs0 + tid;
            atomicAdd(&bact[b], 1);
        }
    }
    __syncthreads();
    const float r0 = rinv[sg*4], r1 = rinv[sg*4+1], r2 = rinv[sg*4+2], r3 = rinv[sg*4+3];
    float* ob = out_nn + (size_t)(bs0 + sg*4) * K_;
#pragma unroll
    for (int j = 0; j < 8; ++j) {
        const int k = kg*8 + j;
        if (k < K_) {
            ob[k]          = acc[0][j] * r0;
            ob[K_ + k]     = acc[1][j] * r1;
            ob[2*K_ + k]   = acc[2][j] * r2;
            ob[3*K_ + k]   = acc[3][j] * r3;
        }
    }
}

// ---------------------------------------------------------------------------
// gemm2p: blocks 0..127 sparse rec1 accumulation over active rows;
//         block 128 computes concept_far -> out[130].
__global__ __launch_bounds__(256) void gemm2p_kernel(
    const float* __restrict__ nn, const float* __restrict__ W1,
    float* __restrict__ hsum, const int* __restrict__ cnt,
    const int* __restrict__ alist, const float* __restrict__ tvn,
    float* __restrict__ out)
{
    __shared__ float red[256];
    const int tid = threadIdx.x;
    if (blockIdx.x == 128) {              // concept_far = (||sum_k tvn_col||^2 - K)/K^2
        float part = 0.f;
        for (int d = tid; d < D_; d += 256) {
            const float4* row = (const float4*)(tvn + (size_t)d * KP_);
            float s = 0.f;
#pragma unroll 8
            for (int i = 0; i < 32; ++i) { float4 v = row[i]; s += v.x + v.y + v.z + v.w; }
            part = fmaf(s, s, part);
        }
        red[tid] = part;
        __syncthreads();
        for (int s = 128; s > 0; s >>= 1) {
            if (tid < s) red[tid] += red[tid + s];
            __syncthreads();
        }
        if (tid == 0) out[130] = (red[0] - (float)K_) / ((float)K_ * (float)K_);
        return;
    }
    __shared__ float nl[K_];
    const int n = *cnt;
    for (int idx = blockIdx.x; idx < n; idx += 128) {
        const int bs = alist[idx];
        const int b  = bs >> 9;
        __syncthreads();
        if (tid < K_) nl[tid] = nn[(size_t)bs * K_ + tid];
        __syncthreads();
        for (int h = tid; h < H_; h += 256) {
            float a = 0.f;
#pragma unroll 4
            for (int k = 0; k < K_; ++k) a = fmaf(nl[k], W1[k*H_ + h], a);
            atomicAdd(&hsum[(size_t)b*H_ + h], fmaxf(a, 0.f));
        }
    }
}

// ---------------------------------------------------------------------------
// gemm3p: feat = (hsum . W2)/S fused into pred partial atomics.
// Inactive batch (the common case) -> immediate exit, pred stays b_cls.
__global__ __launch_bounds__(256) void gemm3p_kernel(
    const float* __restrict__ hsum, const float* __restrict__ W2,
    const float* __restrict__ Wc, const int* __restrict__ bact,
    float* __restrict__ out)
{
    const int b = blockIdx.x >> 2;
    if (bact[b] == 0) return;
    __shared__ float hl[H_];
    __shared__ float red[256];
    const int tid = threadIdx.x;
    const int d = ((blockIdx.x & 3) << 8) + tid;
    for (int h = tid; h < H_; h += 256) hl[h] = hsum[(size_t)b*H_ + h];
    __syncthreads();
    float a = 0.f;
    for (int h = 0; h < H_; ++h) a = fmaf(hl[h], W2[(size_t)h*D_ + d], a);
    a *= (1.0f/512.0f);                   // feat[b][d]
    const float p0 = a * Wc[d*2];
    const float p1 = a * Wc[d*2 + 1];
    red[tid] = p0;
    __syncthreads();
    for (int s = 128; s > 0; s >>= 1) {
        if (tid < s) red[tid] += red[tid + s];
        __syncthreads();
    }
    if (tid == 0) atomicAdd(&out[b*2], red[0]);
    __syncthreads();
    red[tid] = p1;
    __syncthreads();
    for (int s = 128; s > 0; s >>= 1) {
        if (tid < s) red[tid] += red[tid + s];
        __syncthreads();
    }
    if (tid == 0) atomicAdd(&out[b*2 + 1], red[0]);
}

// ---------------------------------------------------------------------------
// topk: per-concept top-16 sum over 32768; per-thread register top16 +
// register/shuffle tournament merge (no LDS candidate array).
// Adds -sum/1600 into out[129].
__global__ __launch_bounds__(256) void topk_kernel(const float* __restrict__ tpnT,
                                                   float* __restrict__ out)
{
    __shared__ float wvv[4];
    __shared__ int   wvi[4];
    const int tid = threadIdx.x;
    const int k = blockIdx.x;
    const float* col = tpnT + (size_t)k * BS_;
    float lst[16];
#pragma unroll
    for (int q = 0; q < 16; ++q) lst[q] = -3.4e38f;
    for (int i = tid; i < BS_; i += 256) {
        const float v = col[i];
        if (v > lst[0]) {                 // insert keeping ascending order
            float nl[16];
#pragma unroll
            for (int q = 0; q < 16; ++q) {
                const bool sh = (q < 15) ? (lst[q+1] < v) : false;
                nl[q] = sh ? lst[q+1] : ((lst[q] < v) ? v : lst[q]);
            }
#pragma unroll
            for (int q = 0; q < 16; ++q) lst[q] = nl[q];
        }
    }
    float sum = 0.f;
    for (int r = 0; r < 16; ++r) {
        float m = lst[0]; int mi = 0;
#pragma unroll
        for (int q = 1; q < 16; ++q) if (lst[q] > m) { m = lst[q]; mi = q; }
        int idx = (tid << 4) | mi;
        for (int off = 32; off > 0; off >>= 1) {
            const float om = __shfl_xor(m, off);
            const int   oi = __shfl_xor(idx, off);
            if (om > m) { m = om; idx = oi; }
        }
        if ((tid & 63) == 0) { wvv[tid >> 6] = m; wvi[tid >> 6] = idx; }
        __syncthreads();
        float gm = wvv[0]; int gi = wvi[0];
#pragma unroll
        for (int w = 1; w < 4; ++w) if (wvv[w] > gm) { gm = wvv[w]; gi = wvi[w]; }
        sum += gm;
        if (tid == (gi >> 4)) {
            const int cq = gi & 15;
#pragma unroll
            for (int q = 0; q < 16; ++q) if (q == cq) lst[q] = -3.4e38f;
        }
        __syncthreads();
    }
    if (tid == 0) atomicAdd(&out[129], sum * (-1.0f/1600.0f));
}

// ---------------------------------------------------------------------------
extern "C" void kernel_launch(void* const* d_in, const int* in_sizes, int n_in,
                              void* d_out, int out_size, void* d_ws, size_t ws_size,
                              hipStream_t stream)
{
    (void)in_sizes; (void)n_in; (void)out_size; (void)ws_size;
    const float* f   = (const float*)d_in[0];
    const float* tv  = (const float*)d_in[1];
    const float* W1  = (const float*)d_in[2];
    const float* W2  = (const float*)d_in[3];
    const float* Wc  = (const float*)d_in[4];
    const float* bc  = (const float*)d_in[5];
    float* out = (float*)d_out;
    float* ws  = (float*)d_ws;

    float* tvn  = ws + OFF_TVN;
    float* tpnT = ws + OFF_TPNT;
    float* hsum = ws + OFF_HSUM;
    int*   ints = (int*)(ws + OFF_INTS);
    int* cnt   = ints;
    int* bact  = ints + 1;
    int* alist = ints + 65;
    float* out_nn = out + 131;

    hipLaunchKernelGGL(prep_kernel,   dim3(641), dim3(256), 0, stream, tv, bc, tvn, hsum, ints, out);
    hipLaunchKernelGGL(gemm1_kernel,  dim3(512), dim3(256), 0, stream, f, tvn, out_nn, tpnT, cnt, bact, alist);
    hipLaunchKernelGGL(gemm2p_kernel, dim3(129), dim3(256), 0, stream, out_nn, W1, hsum, cnt, alist, tvn, out);
    hipLaunchKernelGGL(gemm3p_kernel, dim3(256), dim3(256), 0, stream, hsum, W2, Wc, bact, out);
    hipLaunchKernelGGL(topk_kernel,   dim3(K_),  dim3(256), 0, stream, tpnT, out);
}

// Round 5
// 385.349 us; speedup vs baseline: 1.3448x; 1.3448x over previous
//
#include <hip/hip_runtime.h>
#include <cstdint>
#include <cstddef>

#define B_  64
#define D_  1024
#define S_  512
#define K_  100
#define KP_ 128
#define H_  2048
#define BS_ (B_*S_)   // 32768
#define DC_ 16        // d-chunk per pipeline step
#define NSTEP_ (D_/DC_)

// ---- workspace layout (float offsets) ----
static constexpr size_t OFF_TVN  = 0;                          // [1024][128] padded normalized topics
static constexpr size_t OFF_TPNT = 131072;                     // [100][32768] topic_prob_n transposed
static constexpr size_t OFF_HSUM = OFF_TPNT + (size_t)K_*BS_;  // [64][2048]
static constexpr size_t OFF_INTS = OFF_HSUM + (size_t)B_*H_;   // int region: cnt, bact[64], alist[32768]

#define GLOAD_LDS16(g, l) __builtin_amdgcn_global_load_lds( \
    (const __attribute__((address_space(1))) void*)(g), \
    (__attribute__((address_space(3))) void*)(l), 16, 0, 0)

// ---------------------------------------------------------------------------
// prep: blocks 0..127 normalize topic columns -> tvn[1024][128] (pad cols 0);
//       blocks 128..639 zero hsum; block 640: out scalar init + ints zero.
__global__ __launch_bounds__(256) void prep_kernel(
    const float* __restrict__ tv, const float* __restrict__ bc,
    float* __restrict__ tvn, float* __restrict__ hsum,
    int* __restrict__ ints, float* __restrict__ out)
{
    __shared__ float red[256];
    const int tid = threadIdx.x;
    const int blk = blockIdx.x;
    if (blk < KP_) {
        const int k = blk;
        if (k >= K_) {
            for (int d = tid; d < D_; d += 256) tvn[d*KP_ + k] = 0.f;
            return;
        }
        float ss = 0.f;
        for (int d = tid; d < D_; d += 256) { float v = tv[d*K_ + k]; ss = fmaf(v, v, ss); }
        red[tid] = ss;
        __syncthreads();
        for (int s = 128; s > 0; s >>= 1) {
            if (tid < s) red[tid] += red[tid + s];
            __syncthreads();
        }
        const float inv = 1.0f / fmaxf(sqrtf(red[0]), 1e-12f);
        for (int d = tid; d < D_; d += 256) tvn[d*KP_ + k] = tv[d*K_ + k] * inv;
        return;
    }
    if (blk < KP_ + 512) {
        hsum[(blk - KP_)*256 + tid] = 0.f;       // 512*256 == B_*H_
        return;
    }
    // scalar init block
    if (tid < 128)      out[tid] = bc[tid & 1];  // pred = b_cls (atomics add partials)
    else if (tid < 131) out[tid] = 0.f;          // out[128]=0, sim=0 (+atomics), far placeholder
    if (tid < 65) ints[tid] = 0;                 // cnt + bact[64]
}

// ---------------------------------------------------------------------------
// gemm1: topic_prob = f^T . tvn (fp32 VALU GEMM), LDS double-buffered with
// prefetch issued AFTER the barrier (HBM latency hides under the ~1024-cyc
// compute phase). tvn staged via global_load_lds (no ds_writes); f staged
// through registers (row-norm nsq comes free at ds_write time).
// Grid 512 = 64 b x 8 s-tiles(64). Block 256 threads (4 waves).
// Per-thread tile 4s x 8k: 3 lds reads (dup-broadcast) per 32 FMAs.
__global__ __launch_bounds__(256, 2) void gemm1_kernel(
    const float* __restrict__ f, const float* __restrict__ tvn,
    float* __restrict__ out_nn, float* __restrict__ tpnT,
    int* __restrict__ cnt, int* __restrict__ bact, int* __restrict__ alist)
{
    __shared__ __align__(16) float fs[2][DC_*64];    // 8 KiB
    __shared__ __align__(16) float ts[2][DC_*128];   // 16 KiB
    __shared__ float red[16*64];                     // 4 KiB
    __shared__ float ninv[64];
    __shared__ float rinv[64];

    const int tid  = threadIdx.x;
    const int lane = tid & 63;
    const int wv   = tid >> 6;            // wave 0..3
    const int b    = blockIdx.x >> 3;
    const int s0   = (blockIdx.x & 7) << 6;

    // staging map (f): fj = s-quad, fd = d-row within chunk
    const int fj = tid & 15;
    const int fd = tid >> 4;              // 0..15
    // compute map: sg = s-quad (16 x 4 = 64 s), kg = k-octet (16 x 8 = 128 k)
    const int sg = tid & 15;
    const int kg = tid >> 4;

    const float* fb = f + (size_t)b * D_ * S_ + s0 + fj*4;

    float acc[4][8];
#pragma unroll
    for (int r = 0; r < 4; ++r)
#pragma unroll
        for (int j = 0; j < 8; ++j) acc[r][j] = 0.f;
    float nsq[4] = {0.f, 0.f, 0.f, 0.f};

    // ---- prologue: stage step 0 ----
    {
        const float4 rf = *(const float4*)(fb + (size_t)fd * S_);
        GLOAD_LDS16(tvn + (4*wv)*KP_     + lane*4, &ts[0][(4*wv)*KP_]);
        GLOAD_LDS16(tvn + (4*wv + 2)*KP_ + lane*4, &ts[0][(4*wv + 2)*KP_]);
        *(float4*)&fs[0][fd*64 + fj*4] = rf;
        nsq[0] = fmaf(rf.x, rf.x, nsq[0]);
        nsq[1] = fmaf(rf.y, rf.y, nsq[1]);
        nsq[2] = fmaf(rf.z, rf.z, nsq[2]);
        nsq[3] = fmaf(rf.w, rf.w, nsq[3]);
    }

    for (int step = 0; step < NSTEP_; ++step) {
        const int cur = step & 1;
        __syncthreads();                  // ds_writes visible + gload vmcnt drained
        float4 rfn;
        if (step < NSTEP_ - 1) {          // issue next-step loads AFTER barrier
            const int d0n = (step + 1) * DC_;
            rfn = *(const float4*)(fb + (size_t)(d0n + fd) * S_);
            const float* tsrc = tvn + (size_t)d0n * KP_;
            GLOAD_LDS16(tsrc + (4*wv)*KP_     + lane*4, &ts[cur ^ 1][(4*wv)*KP_]);
            GLOAD_LDS16(tsrc + (4*wv + 2)*KP_ + lane*4, &ts[cur ^ 1][(4*wv + 2)*KP_]);
        }
        const float* fcur = fs[cur];
        const float* tcur = ts[cur];
#pragma unroll
        for (int di = 0; di < DC_; ++di) {
            const float4 a  = *(const float4*)&fcur[di*64 + sg*4];
            const float4 w0 = *(const float4*)&tcur[di*128 + kg*8];
            const float4 w1 = *(const float4*)&tcur[di*128 + kg*8 + 4];
            const float w[8] = {w0.x,w0.y,w0.z,w0.w,w1.x,w1.y,w1.z,w1.w};
#pragma unroll
            for (int j = 0; j < 8; ++j) {
                acc[0][j] = fmaf(a.x, w[j], acc[0][j]);
                acc[1][j] = fmaf(a.y, w[j], acc[1][j]);
                acc[2][j] = fmaf(a.z, w[j], acc[2][j]);
                acc[3][j] = fmaf(a.w, w[j], acc[3][j]);
            }
        }
        if (step < NSTEP_ - 1) {
            *(float4*)&fs[cur ^ 1][fd*64 + fj*4] = rfn;
            nsq[0] = fmaf(rfn.x, rfn.x, nsq[0]);
            nsq[1] = fmaf(rfn.y, rfn.y, nsq[1]);
            nsq[2] = fmaf(rfn.z, rfn.z, nsq[2]);
            nsq[3] = fmaf(rfn.w, rfn.w, nsq[3]);
        }
    }

    // ---- epilogue ----
    // row norms: thread (fj,fd) covered d = {fd + 16*step}; reduce 16 fd-groups.
    __syncthreads();
    red[fd*64 + fj*4 + 0] = nsq[0];
    red[fd*64 + fj*4 + 1] = nsq[1];
    red[fd*64 + fj*4 + 2] = nsq[2];
    red[fd*64 + fj*4 + 3] = nsq[3];
    __syncthreads();
    if (tid < 64) {
        float t = 0.f;
#pragma unroll
        for (int g = 0; g < 16; ++g) t += red[g*64 + tid];
        ninv[tid] = 1.0f / fmaxf(sqrtf(t), 1e-12f);
    }
    __syncthreads();

    const int bs0 = b * S_ + s0;
    const float inv0 = ninv[sg*4], inv1 = ninv[sg*4+1], inv2 = ninv[sg*4+2], inv3 = ninv[sg*4+3];
    float rowp[4] = {0.f, 0.f, 0.f, 0.f};

#pragma unroll
    for (int j = 0; j < 8; ++j) {
        const int k = kg*8 + j;
        const float t0 = acc[0][j]*inv0, t1 = acc[1][j]*inv1,
                    t2 = acc[2][j]*inv2, t3 = acc[3][j]*inv3;
        acc[0][j] = (t0 > 0.3f) ? acc[0][j] : 0.f;   // topic_prob * mask
        acc[1][j] = (t1 > 0.3f) ? acc[1][j] : 0.f;
        acc[2][j] = (t2 > 0.3f) ? acc[2][j] : 0.f;
        acc[3][j] = (t3 > 0.3f) ? acc[3][j] : 0.f;
        rowp[0] += acc[0][j]; rowp[1] += acc[1][j];
        rowp[2] += acc[2][j]; rowp[3] += acc[3][j];
        if (k < K_) {                     // topic_prob_n transposed (coalesced float4)
            float4 v; v.x = t0; v.y = t1; v.z = t2; v.w = t3;
            *(float4*)&tpnT[(size_t)k * BS_ + bs0 + sg*4] = v;
        }
    }

    // row sums: reduce across 16 k-groups
    __syncthreads();
#pragma unroll
    for (int r = 0; r < 4; ++r) red[kg*64 + sg*4 + r] = rowp[r];
    __syncthreads();
    if (tid < 64) {
        float t = 0.f;
#pragma unroll
        for (int g = 0; g < 16; ++g) t += red[g*64 + tid];
        rinv[tid] = 1.0f / (t + 0.001f);
        if (t > 0.f) {                    // any unmasked concept in this row
            const int pos = atomicAdd(cnt, 1);
            alist[pos] = bs0 + tid;
            atomicAdd(&bact[b], 1);
        }
    }
    __syncthreads();
    const float r0 = rinv[sg*4], r1 = rinv[sg*4+1], r2 = rinv[sg*4+2], r3 = rinv[sg*4+3];
    float* ob = out_nn + (size_t)(bs0 + sg*4) * K_;
#pragma unroll
    for (int j = 0; j < 8; ++j) {
        const int k = kg*8 + j;
        if (k < K_) {
            ob[k]          = acc[0][j] * r0;
            ob[K_ + k]     = acc[1][j] * r1;
            ob[2*K_ + k]   = acc[2][j] * r2;
            ob[3*K_ + k]   = acc[3][j] * r3;
        }
    }
}

// ---------------------------------------------------------------------------
// gemm2p: blocks 0..127 sparse rec1 accumulation over active rows;
//         block 128 computes concept_far -> out[130].
__global__ __launch_bounds__(256) void gemm2p_kernel(
    const float* __restrict__ nn, const float* __restrict__ W1,
    float* __restrict__ hsum, const int* __restrict__ cnt,
    const int* __restrict__ alist, const float* __restrict__ tvn,
    float* __restrict__ out)
{
    __shared__ float red[256];
    const int tid = threadIdx.x;
    if (blockIdx.x == 128) {              // concept_far = (||sum_k tvn_col||^2 - K)/K^2
        float part = 0.f;
        for (int d = tid; d < D_; d += 256) {
            const float4* row = (const float4*)(tvn + (size_t)d * KP_);
            float s = 0.f;
#pragma unroll 8
            for (int i = 0; i < 32; ++i) { float4 v = row[i]; s += v.x + v.y + v.z + v.w; }
            part = fmaf(s, s, part);
        }
        red[tid] = part;
        __syncthreads();
        for (int s = 128; s > 0; s >>= 1) {
            if (tid < s) red[tid] += red[tid + s];
            __syncthreads();
        }
        if (tid == 0) out[130] = (red[0] - (float)K_) / ((float)K_ * (float)K_);
        return;
    }
    __shared__ float nl[K_];
    const int n = *cnt;
    for (int idx = blockIdx.x; idx < n; idx += 128) {
        const int bs = alist[idx];
        const int b  = bs >> 9;
        __syncthreads();
        if (tid < K_) nl[tid] = nn[(size_t)bs * K_ + tid];
        __syncthreads();
        for (int h = tid; h < H_; h += 256) {
            float a = 0.f;
#pragma unroll 4
            for (int k = 0; k < K_; ++k) a = fmaf(nl[k], W1[k*H_ + h], a);
            atomicAdd(&hsum[(size_t)b*H_ + h], fmaxf(a, 0.f));
        }
    }
}

// ---------------------------------------------------------------------------
// gemm3p: feat = (hsum . W2)/S fused into pred partial atomics.
// Inactive batch (the common case) -> immediate exit, pred stays b_cls.
__global__ __launch_bounds__(256) void gemm3p_kernel(
    const float* __restrict__ hsum, const float* __restrict__ W2,
    const float* __restrict__ Wc, const int* __restrict__ bact,
    float* __restrict__ out)
{
    const int b = blockIdx.x >> 2;
    if (bact[b] == 0) return;
    __shared__ float hl[H_];
    __shared__ float red[256];
    const int tid = threadIdx.x;
    const int d = ((blockIdx.x & 3) << 8) + tid;
    for (int h = tid; h < H_; h += 256) hl[h] = hsum[(size_t)b*H_ + h];
    __syncthreads();
    float a = 0.f;
    for (int h = 0; h < H_; ++h) a = fmaf(hl[h], W2[(size_t)h*D_ + d], a);
    a *= (1.0f/512.0f);                   // feat[b][d]
    const float p0 = a * Wc[d*2];
    const float p1 = a * Wc[d*2 + 1];
    red[tid] = p0;
    __syncthreads();
    for (int s = 128; s > 0; s >>= 1) {
        if (tid < s) red[tid] += red[tid + s];
        __syncthreads();
    }
    if (tid == 0) atomicAdd(&out[b*2], red[0]);
    __syncthreads();
    red[tid] = p1;
    __syncthreads();
    for (int s = 128; s > 0; s >>= 1) {
        if (tid < s) red[tid] += red[tid + s];
        __syncthreads();
    }
    if (tid == 0) atomicAdd(&out[b*2 + 1], red[0]);
}

// ---------------------------------------------------------------------------
// topk: per-concept top-16 sum over 32768; per-thread register top16 +
// register/shuffle tournament merge (no LDS candidate array).
// Adds -sum/1600 into out[129].
__global__ __launch_bounds__(256) void topk_kernel(const float* __restrict__ tpnT,
                                                   float* __restrict__ out)
{
    __shared__ float wvv[4];
    __shared__ int   wvi[4];
    const int tid = threadIdx.x;
    const int k = blockIdx.x;
    const float* col = tpnT + (size_t)k * BS_;
    float lst[16];
#pragma unroll
    for (int q = 0; q < 16; ++q) lst[q] = -3.4e38f;
    for (int i = tid; i < BS_; i += 256) {
        const float v = col[i];
        if (v > lst[0]) {                 // insert keeping ascending order
            float nl[16];
#pragma unroll
            for (int q = 0; q < 16; ++q) {
                const bool sh = (q < 15) ? (lst[q+1] < v) : false;
                nl[q] = sh ? lst[q+1] : ((lst[q] < v) ? v : lst[q]);
            }
#pragma unroll
            for (int q = 0; q < 16; ++q) lst[q] = nl[q];
        }
    }
    float sum = 0.f;
    for (int r = 0; r < 16; ++r) {
        float m = lst[0]; int mi = 0;
#pragma unroll
        for (int q = 1; q < 16; ++q) if (lst[q] > m) { m = lst[q]; mi = q; }
        int idx = (tid << 4) | mi;
        for (int off = 32; off > 0; off >>= 1) {
            const float om = __shfl_xor(m, off);
            const int   oi = __shfl_xor(idx, off);
            if (om > m) { m = om; idx = oi; }
        }
        if ((tid & 63) == 0) { wvv[tid >> 6] = m; wvi[tid >> 6] = idx; }
        __syncthreads();
        float gm = wvv[0]; int gi = wvi[0];
#pragma unroll
        for (int w = 1; w < 4; ++w) if (wvv[w] > gm) { gm = wvv[w]; gi = wvi[w]; }
        sum += gm;
        if (tid == (gi >> 4)) {
            const int cq = gi & 15;
#pragma unroll
            for (int q = 0; q < 16; ++q) if (q == cq) lst[q] = -3.4e38f;
        }
        __syncthreads();
    }
    if (tid == 0) atomicAdd(&out[129], sum * (-1.0f/1600.0f));
}

// ---------------------------------------------------------------------------
extern "C" void kernel_launch(void* const* d_in, const int* in_sizes, int n_in,
                              void* d_out, int out_size, void* d_ws, size_t ws_size,
                              hipStream_t stream)
{
    (void)in_sizes; (void)n_in; (void)out_size; (void)ws_size;
    const float* f   = (const float*)d_in[0];
    const float* tv  = (const float*)d_in[1];
    const float* W1  = (const float*)d_in[2];
    const float* W2  = (const float*)d_in[3];
    const float* Wc  = (const float*)d_in[4];
    const float* bc  = (const float*)d_in[5];
    float* out = (float*)d_out;
    float* ws  = (float*)d_ws;

    float* tvn  = ws + OFF_TVN;
    float* tpnT = ws + OFF_TPNT;
    float* hsum = ws + OFF_HSUM;
    int*   ints = (int*)(ws + OFF_INTS);
    int* cnt   = ints;
    int* bact  = ints + 1;
    int* alist = ints + 65;
    float* out_nn = out + 131;

    hipLaunchKernelGGL(prep_kernel,   dim3(641), dim3(256), 0, stream, tv, bc, tvn, hsum, ints, out);
    hipLaunchKernelGGL(gemm1_kernel,  dim3(512), dim3(256), 0, stream, f, tvn, out_nn, tpnT, cnt, bact, alist);
    hipLaunchKernelGGL(gemm2p_kernel, dim3(129), dim3(256), 0, stream, out_nn, W1, hsum, cnt, alist, tvn, out);
    hipLaunchKernelGGL(gemm3p_kernel, dim3(256), dim3(256), 0, stream, hsum, W2, Wc, bact, out);
    hipLaunchKernelGGL(topk_kernel,   dim3(K_),  dim3(256), 0, stream, tpnT, out);
}